// Round 2
// baseline (422.644 us; speedup 1.0000x reference)
//
#include <hip/hip_runtime.h>
#include <hip/hip_bf16.h>

// GCN layer: out = leaky( (adj @ (node @ W^T)) / deg + b )
// Kernel 1: Ht[b][o][j] = sum_f node[b,j,f]*W[o,f]  (bf16, transposed for B-frag reads)
// Kernel 2: stream adj once, fused row-sums (deg), MFMA adj@Ht^T, epilogue /deg+bias+leaky.

typedef __attribute__((ext_vector_type(8))) short bf16x8;   // 8 bf16 = 4 VGPR (MFMA A/B frag)
typedef __attribute__((ext_vector_type(4))) float f32x4;    // MFMA C/D frag

// fp32 -> bf16 round-to-nearest-even, via integer bit math (bit-exact with
// __float2bfloat16_rn for finite inputs; avoids non-trivially-copyable HIP types)
__device__ __forceinline__ unsigned f2bf(float x) {
  unsigned u = __builtin_bit_cast(unsigned, x);
  u += 0x7FFFu + ((u >> 16) & 1u);
  return u >> 16;
}
__device__ __forceinline__ int f2bf2(float x, float y) {
  return (int)(f2bf(x) | (f2bf(y) << 16));
}

#define JPAD 136   // 128 + 8 bf16 pad: row stride 272B -> 2-way LDS aliasing (free)
#define KP   72    // 64 + 8 bf16 pad: row stride 144B

// ---------------- Kernel 1: Ht = (node @ W^T)^T in bf16 ----------------
__global__ __launch_bounds__(256) void k_ht(const float* __restrict__ node,
                                            const float* __restrict__ W,
                                            ushort* __restrict__ Ht) {
  __shared__ short nt[128 * JPAD];  // node tile [j][f]; reused as [o][j] out-staging
  __shared__ short wt[128 * JPAD];  // W [o][f] bf16
  const int b = blockIdx.y, jt = blockIdx.x, t = threadIdx.x;
  const float4* nbase = (const float4*)(node + (size_t)(b * 1024 + jt * 128) * 128);
  const float4* wbase = (const float4*)W;

  // stage node tile (128x128 f32) + W, converting to bf16
  #pragma unroll
  for (int p = 0; p < 16; p++) {
    int idx = t + 256 * p;
    int r = idx >> 5, c4 = idx & 31;
    float4 v = nbase[idx];
    int2 s; s.x = f2bf2(v.x, v.y); s.y = f2bf2(v.z, v.w);
    *(int2*)&nt[r * JPAD + c4 * 4] = s;
    float4 wv = wbase[idx];
    int2 sw; sw.x = f2bf2(wv.x, wv.y); sw.y = f2bf2(wv.z, wv.w);
    *(int2*)&wt[r * JPAD + c4 * 4] = sw;
  }
  __syncthreads();

  const int lane = t & 63, wid = t >> 6;
  const int q = lane >> 4, r = lane & 15;
  const int wm = wid & 1, wn = wid >> 1;   // 2x2 waves, 64x64 each
  f32x4 acc[4][4] = {};
  #pragma unroll
  for (int ks = 0; ks < 4; ks++) {        // K = 128 over f, 32/step
    bf16x8 af[4], bg[4];
    #pragma unroll
    for (int mi = 0; mi < 4; mi++)
      af[mi] = *(const bf16x8*)&nt[(wm * 64 + mi * 16 + r) * JPAD + ks * 32 + q * 8];
    #pragma unroll
    for (int ni = 0; ni < 4; ni++)
      bg[ni] = *(const bf16x8*)&wt[(wn * 64 + ni * 16 + r) * JPAD + ks * 32 + q * 8];
    #pragma unroll
    for (int mi = 0; mi < 4; mi++)
      #pragma unroll
      for (int ni = 0; ni < 4; ni++)
        acc[mi][ni] = __builtin_amdgcn_mfma_f32_16x16x32_bf16(af[mi], bg[ni], acc[mi][ni], 0, 0, 0);
  }
  __syncthreads();

  // D[row=4q+v][col=r] -> stage transposed [o][j] in LDS, then coalesced global store
  #pragma unroll
  for (int mi = 0; mi < 4; mi++)
    #pragma unroll
    for (int ni = 0; ni < 4; ni++)
      #pragma unroll
      for (int v = 0; v < 4; v++) {
        int j = wm * 64 + mi * 16 + q * 4 + v;
        int o = wn * 64 + ni * 16 + r;
        nt[o * JPAD + j] = (short)f2bf(acc[mi][ni][v]);
      }
  __syncthreads();
  {
    int o = t >> 1, half = t & 1;
    const int4* src = (const int4*)&nt[o * JPAD + half * 64];
    int4* dst = (int4*)(Ht + (size_t)b * 131072 + (size_t)o * 1024 + jt * 128 + half * 64);
    #pragma unroll
    for (int i = 0; i < 8; i++) dst[i] = src[i];
  }
}

// ---------------- Kernel 2: out = leaky(adj @ Ht^T / deg + bias) ----------------
__global__ __launch_bounds__(256) void k_main(const float* __restrict__ adj,
                                              const ushort* __restrict__ Ht,
                                              const float* __restrict__ bias,
                                              float* __restrict__ out) {
  __shared__ short at[128 * KP];   // adj tile [i][j] bf16
  __shared__ short ht[128 * KP];   // Ht tile [o][j] bf16
  __shared__ float deg[128];
  const int b = blockIdx.y, it = blockIdx.x, t = threadIdx.x;
  const float4* abase = (const float4*)(adj + (size_t)(b * 1024 + it * 128) * 1024);
  const int4* hbase = (const int4*)(Ht + (size_t)b * 131072);  // row = 128 int4
  const int lane = t & 63, wid = t >> 6;
  const int q = lane >> 4, r = lane & 15;
  const int wm = wid & 1, wn = wid >> 1;
  const int arow = t >> 4, ac4 = t & 15;   // adj staging: rows arow+16p, float4 col ac4
  const int hrow = t >> 3, hc8 = t & 7;    // Ht staging: rows hrow+32p, int4 col hc8
  f32x4 acc[4][4] = {};
  float rs[8] = {0, 0, 0, 0, 0, 0, 0, 0};  // per-thread row-sum partials (fixed rows)
  float bias_r[4];
  #pragma unroll
  for (int ni = 0; ni < 4; ni++) bias_r[ni] = bias[wn * 64 + ni * 16 + r];

  for (int kt = 0; kt < 16; kt++) {        // K = 1024 over j, BK = 64
    float4 av[8];
    #pragma unroll
    for (int p = 0; p < 8; p++)
      av[p] = abase[(size_t)(arow + 16 * p) * 256 + kt * 16 + ac4];
    int4 hv[4];
    #pragma unroll
    for (int p = 0; p < 4; p++)
      hv[p] = hbase[(size_t)(hrow + 32 * p) * 128 + kt * 8 + hc8];
    __syncthreads();  // previous MFMA stage done reading LDS
    #pragma unroll
    for (int p = 0; p < 8; p++) {
      rs[p] += (av[p].x + av[p].y) + (av[p].z + av[p].w);   // fused deg accumulation
      int2 s; s.x = f2bf2(av[p].x, av[p].y); s.y = f2bf2(av[p].z, av[p].w);
      *(int2*)&at[(arow + 16 * p) * KP + ac4 * 4] = s;
    }
    #pragma unroll
    for (int p = 0; p < 4; p++)
      *(int4*)&ht[(hrow + 32 * p) * KP + hc8 * 8] = hv[p];
    __syncthreads();
    #pragma unroll
    for (int ks = 0; ks < 2; ks++) {
      bf16x8 af[4], bg[4];
      #pragma unroll
      for (int mi = 0; mi < 4; mi++)
        af[mi] = *(const bf16x8*)&at[(wm * 64 + mi * 16 + r) * KP + ks * 32 + q * 8];
      #pragma unroll
      for (int ni = 0; ni < 4; ni++)
        bg[ni] = *(const bf16x8*)&ht[(wn * 64 + ni * 16 + r) * KP + ks * 32 + q * 8];
      #pragma unroll
      for (int mi = 0; mi < 4; mi++)
        #pragma unroll
        for (int ni = 0; ni < 4; ni++)
          acc[mi][ni] = __builtin_amdgcn_mfma_f32_16x16x32_bf16(af[mi], bg[ni], acc[mi][ni], 0, 0, 0);
    }
  }

  // deg: reduce across the 16 threads sharing each row (consecutive lanes)
  #pragma unroll
  for (int p = 0; p < 8; p++) {
    float v = rs[p];
    v += __shfl_down(v, 8, 16);
    v += __shfl_down(v, 4, 16);
    v += __shfl_down(v, 2, 16);
    v += __shfl_down(v, 1, 16);
    rs[p] = v;
  }
  if ((t & 15) == 0) {
    #pragma unroll
    for (int p = 0; p < 8; p++) deg[arow + 16 * p] = rs[p];
  }
  __syncthreads();

  float* obase = out + (size_t)(b * 1024 + it * 128) * 128;
  #pragma unroll
  for (int mi = 0; mi < 4; mi++)
    #pragma unroll
    for (int v = 0; v < 4; v++) {
      int i = wm * 64 + mi * 16 + q * 4 + v;
      float rd = 1.0f / deg[i];
      #pragma unroll
      for (int ni = 0; ni < 4; ni++) {
        int o = wn * 64 + ni * 16 + r;
        float val = acc[mi][ni][v] * rd + bias_r[ni];
        val = val >= 0.0f ? val : 0.01f * val;
        obase[(size_t)i * 128 + o] = val;
      }
    }
}

// ---------------- Fallback (ws too small): straightforward fp32 ----------------
__global__ __launch_bounds__(256) void k_fallback(const float* __restrict__ node,
                                                  const float* __restrict__ adj,
                                                  const float* __restrict__ W,
                                                  const float* __restrict__ bias,
                                                  float* __restrict__ out) {
  __shared__ float red[256];
  __shared__ float agg[128];
  const int b = blockIdx.y, i = blockIdx.x, t = threadIdx.x;
  const float* arow = adj + (size_t)(b * 1024 + i) * 1024;
  float s = 0.f;
  for (int j = t; j < 1024; j += 256) s += arow[j];
  red[t] = s;
  __syncthreads();
  if (t < 128) red[t] += red[t + 128];
  __syncthreads();
  if (t < 64) {
    float v2 = red[t] + red[t + 64];
    #pragma unroll
    for (int off = 32; off; off >>= 1) v2 += __shfl_down(v2, off);
    if (t == 0) red[0] = v2;
  }
  __syncthreads();
  const float rdeg = 1.0f / red[0];
  const int f = t & 127, half = t >> 7;
  const float* nb = node + (size_t)b * 1024 * 128;
  float a = 0.f;
  for (int j = half * 512; j < half * 512 + 512; j++)
    a += arow[j] * nb[(size_t)j * 128 + f];
  __syncthreads();
  if (half == 0) agg[f] = a;
  __syncthreads();
  if (half == 1) agg[f] += a;
  __syncthreads();
  if (t < 128) {
    const float* wr = W + t * 128;
    float o = 0.f;
    for (int f2 = 0; f2 < 128; f2++) o += agg[f2] * wr[f2];
    o = o * rdeg + bias[t];
    out[(size_t)(b * 1024 + i) * 128 + t] = o >= 0.f ? o : 0.01f * o;
  }
}

extern "C" void kernel_launch(void* const* d_in, const int* in_sizes, int n_in,
                              void* d_out, int out_size, void* d_ws, size_t ws_size,
                              hipStream_t stream) {
  const float* node = (const float*)d_in[0];   // [64,1024,128]
  const float* adj  = (const float*)d_in[1];   // [64,1024,1024]
  const float* W    = (const float*)d_in[2];   // [128,128]
  const float* bias = (const float*)d_in[3];   // [128]
  float* out = (float*)d_out;                  // [64,1024,128]
  const size_t ht_bytes = (size_t)64 * 128 * 1024 * 2;  // 16 MiB bf16 Ht
  if (ws_size >= ht_bytes) {
    ushort* Ht = (ushort*)d_ws;
    k_ht<<<dim3(8, 64), 256, 0, stream>>>(node, W, Ht);
    k_main<<<dim3(8, 64), 256, 0, stream>>>(adj, Ht, bias, out);
  } else {
    k_fallback<<<dim3(1024, 64), 256, 0, stream>>>(node, adj, W, bias, out);
  }
}